// Round 12
// baseline (316.012 us; speedup 1.0000x reference)
//
#include <hip/hip_runtime.h>

// PosEvalModel: embed-gather + GRU(L=128, N=3200) + proj + GRU(C=50, N=64) + final.
// v12 = r11 with the x-LDS round-trip deleted:
//   - x A-frags loaded DIRECTLY from global emb per wave (coalesced 16B/lane, L1-hot),
//     issued one step ahead (T14), packed to bf16 in regs (no xbuf, no stage writes)
//   - x-MFMA carried one step ahead: Dnext = bias + x(s+1)@Wx computed after gates(s);
//     post-barrier path is only Ah -> h-MFMA -> gates. Accum order bit-identical to r11.
//  K0 m2:  M2[384][129] = ctx_w_ih @ proj_w (+b2)
//  K1 gru<EMB>: ast recurrence (8 waves, 16 rows, 24 MFMA/wave/step)
//  K2 cgi: cgi[c,b][384] = M2 @ [hT;ind] + b2
//  K3 gru<!EMB>: ctx recurrence (r11-exact) + fused final matmul epilogue

#define V_VOCAB 100008

typedef __attribute__((ext_vector_type(8))) short bf16x8;
typedef __attribute__((ext_vector_type(4))) float f32x4;

__device__ __forceinline__ unsigned pk_bf16(float lo, float hi){
  unsigned r;
  asm("v_cvt_pk_bf16_f32 %0, %1, %2" : "=v"(r) : "v"(lo), "v"(hi));
  return r;
}
__device__ __forceinline__ unsigned short bf1(float x){   // f32->bf16 via HW cvt
  return (unsigned short)pk_bf16(x, x);
}
__device__ __forceinline__ bf16x8 pack8(f32x4 a, f32x4 b){
  union { unsigned u[4]; bf16x8 v; } x;
  x.u[0] = pk_bf16(a[0], a[1]);
  x.u[1] = pk_bf16(a[2], a[3]);
  x.u[2] = pk_bf16(b[0], b[1]);
  x.u[3] = pk_bf16(b[2], b[3]);
  return x.v;
}
__device__ __forceinline__ float bf2f(unsigned bits){
  union { unsigned u; float f; } x; x.u = bits << 16; return x.f;
}
__device__ __forceinline__ float fexp2(float x){ return __builtin_amdgcn_exp2f(x); }
__device__ __forceinline__ float frcp(float x){ return __builtin_amdgcn_rcpf(x); }
__device__ __forceinline__ float sigm(float x){ return frcp(1.f + fexp2(x * -1.44269504089f)); }
__device__ __forceinline__ float tanh_fast(float x){
  float t = fexp2(x * -2.88539008178f);        // e^{-2x}
  return (1.f - t) * frcp(1.f + t);
}
// element index of the 8-elem chunk (row, ch=k>>3) in a 16x128 bf16 tile, swizzled
__device__ __forceinline__ int hchunk(int row, int ch){
  return row*128 + ((ch ^ row ^ (row >> 2)) & 15)*8;
}

// ---------------- K0: M2 = ctx_w_ih @ proj_w (+b2) ----------------
__global__ __launch_bounds__(256)
void m2_kernel(const float* __restrict__ wcih, const float* __restrict__ pw,
               const float* __restrict__ pb, const float* __restrict__ bcih,
               const float* __restrict__ bchh, float* __restrict__ M2,
               float* __restrict__ b2)
{
  int t = blockIdx.x*256 + threadIdx.x;
  if (t >= 384*130) return;
  int o = t / 130, kk = t % 130;
  const float* wr = wcih + o*128;
  if (kk < 129){
    float acc = 0.f;
    for (int m = 0; m < 128; ++m) acc += wr[m] * pw[m*129 + kk];
    M2[o*132 + kk] = acc;                       // padded stride 132
  } else {
    float acc = bcih[o] + (o < 256 ? bchh[o] : 0.f);
    for (int m = 0; m < 128; ++m) acc += wr[m] * pb[m];
    b2[o] = acc;
  }
}

// ---------------- K1/K3: GRU recurrence (8 waves / 512 thr / 16 rows) ----------------
// Wave w owns gate-cols {w*16..w*16+15} (r,z,n).
// EMB: post-barrier = Ah read + h-MFMA + gates only; x-part of step s+1 precomputed
//      in step s from direct global x-frag loads (issued at s-1, reg-held).
// !EMB: r11-exact DEPTH-deep gi_f32 prefetch (ctx path).
template<int STEPS, int DEPTH, bool EMB, bool FINAL>
__global__ __launch_bounds__(512, 1)
void gru_kernel(const int* __restrict__ tok_ids,
                const float* __restrict__ emb,
                const float* __restrict__ gi_f32,
                const float* __restrict__ whh,
                const float* __restrict__ wih,
                const float* __restrict__ bih,
                const float* __restrict__ bhh,
                const float* __restrict__ hinit,
                float* __restrict__ hout,
                const float* __restrict__ fw,
                const float* __restrict__ fb,
                float* __restrict__ outp)
{
  __shared__ unsigned short hbuf[2][2048];      // [buf][16 rows x 128 k] bf16, swizzled
  __shared__ int toks[EMB ? 2048 : 2];          // emb byte-offsets [16 rows][128 steps]
  const int tid = threadIdx.x;
  const int w = tid >> 6, lane = tid & 63, c = lane & 15, q = lane >> 4;
  const int n0 = blockIdx.x * 16;
  const int w16c = w*16 + c;

  if constexpr (EMB){
    for (int i = tid; i < 2048; i += 512) toks[i] = tok_ids[n0*128 + i] << 9;  // *512B
  }
  // weight fragments, UNSCALED bf16 (B layout: col = lane&15 = o, k = kt*32 + q*8 + e)
  bf16x8 Bh[3][4], Bx[3][4];
#pragma unroll
  for (int g = 0; g < 3; ++g)
#pragma unroll
    for (int kt = 0; kt < 4; ++kt){
      int o = g*128 + w16c;
      const f32x4* ph = (const f32x4*)(whh + o*128 + kt*32 + q*8);
      Bh[g][kt] = pack8(ph[0], ph[1]);
      if constexpr (EMB){
        const f32x4* px = (const f32x4*)(wih + o*128 + kt*32 + q*8);
        Bx[g][kt] = pack8(px[0], px[1]);
      }
    }
  float cr, cz, cin;
  const float bn = bhh[256 + w16c];             // b_hh_n (multiplied by r)
  if constexpr (EMB){
    cr  = bih[w16c]       + bhh[w16c];          // b_ih_r + b_hh_r
    cz  = bih[128 + w16c] + bhh[128 + w16c];    // b_ih_z + b_hh_z
    cin = bih[256 + w16c];                      // b_ih_n (outside r*(...))
  }
  float h_old[4];
  {
    float h0 = hinit[w16c];
#pragma unroll
    for (int r = 0; r < 4; ++r) h_old[r] = h0;
  }
  for (int i = tid; i < 2048; i += 512){
    int row = i >> 7, k = i & 127;
    hbuf[0][hchunk(row, k >> 3) + (k & 7)] = bf1(hinit[k]);
  }
  __syncthreads();                              // hbuf[0] + toks visible

  if constexpr (EMB){
    // x A-frag direct loads: lane (c,q) reads emb row toks[c][t], 16B at kt*128+q*32(+16)
    f32x4 EF[8];
    auto issue_x = [&](int t){
      int tt = t < STEPS ? t : STEPS - 1;       // tail-clamped, uniform count
      const char* pb = (const char*)emb + (size_t)(unsigned)toks[c*128 + tt] + q*32;
#pragma unroll
      for (int kt = 0; kt < 4; ++kt){
        EF[2*kt]   = *(const f32x4*)(pb + kt*128);
        EF[2*kt+1] = *(const f32x4*)(pb + kt*128 + 16);
      }
    };
    f32x4 P0, P1, P3, Q0, Q1, Q3;               // two banks: x-part + bias of a step
    issue_x(0);
    {
      bf16x8 AX[4];
#pragma unroll
      for (int kt = 0; kt < 4; ++kt) AX[kt] = pack8(EF[2*kt], EF[2*kt+1]);
#pragma unroll
      for (int r = 0; r < 4; ++r){ P0[r] = cr; P1[r] = cz; P3[r] = cin; }
#pragma unroll
      for (int kt = 0; kt < 4; ++kt){
        P0 = __builtin_amdgcn_mfma_f32_16x16x32_bf16(AX[kt], Bx[0][kt], P0, 0,0,0);
        P1 = __builtin_amdgcn_mfma_f32_16x16x32_bf16(AX[kt], Bx[1][kt], P1, 0,0,0);
        P3 = __builtin_amdgcn_mfma_f32_16x16x32_bf16(AX[kt], Bx[2][kt], P3, 0,0,0);
      }
    }
    issue_x(1);

    auto body = [&](int s, f32x4& C0, f32x4& C1, f32x4& C3,
                           f32x4& N0, f32x4& N1, f32x4& N3){
      const int cur = s & 1, nxt = cur ^ 1;
      // post-barrier critical path: Ah -> h-MFMA -> gates
      bf16x8 Ah[4];
#pragma unroll
      for (int kt = 0; kt < 4; ++kt)
        Ah[kt] = *(const bf16x8*)&hbuf[cur][hchunk(c, kt*4 + q)];
      f32x4 D2;
#pragma unroll
      for (int r = 0; r < 4; ++r) D2[r] = bn;
#pragma unroll
      for (int kt = 0; kt < 4; ++kt){
        C0 = __builtin_amdgcn_mfma_f32_16x16x32_bf16(Ah[kt], Bh[0][kt], C0, 0,0,0);
        C1 = __builtin_amdgcn_mfma_f32_16x16x32_bf16(Ah[kt], Bh[1][kt], C1, 0,0,0);
        D2 = __builtin_amdgcn_mfma_f32_16x16x32_bf16(Ah[kt], Bh[2][kt], D2, 0,0,0);
      }
      // gates: r3-exact (D row = q*4+r, col = w16c -> lane-local)
#pragma unroll
      for (int r = 0; r < 4; ++r){
        float rr = sigm(C0[r]);
        float z  = sigm(C1[r]);
        float nn = tanh_fast(C3[r] + rr * D2[r]);
        h_old[r] = nn + z*(h_old[r] - nn);
      }
      // x-part of step s+1 (EF holds x(s+1), issued at s-1; vmcnt auto-counted)
      bf16x8 AX[4];
#pragma unroll
      for (int kt = 0; kt < 4; ++kt) AX[kt] = pack8(EF[2*kt], EF[2*kt+1]);
#pragma unroll
      for (int r = 0; r < 4; ++r){ N0[r] = cr; N1[r] = cz; N3[r] = cin; }
#pragma unroll
      for (int kt = 0; kt < 4; ++kt){
        N0 = __builtin_amdgcn_mfma_f32_16x16x32_bf16(AX[kt], Bx[0][kt], N0, 0,0,0);
        N1 = __builtin_amdgcn_mfma_f32_16x16x32_bf16(AX[kt], Bx[1][kt], N1, 0,0,0);
        N3 = __builtin_amdgcn_mfma_f32_16x16x32_bf16(AX[kt], Bx[2][kt], N3, 0,0,0);
      }
      issue_x(s + 2);                           // refill EF with x(s+2), in flight 1 step
      // h write + step barrier
#pragma unroll
      for (int r = 0; r < 4; ++r)
        hbuf[nxt][hchunk(q*4 + r, w*2 + (c >> 3)) + (c & 7)] = bf1(h_old[r]);
      asm volatile("s_waitcnt lgkmcnt(0)" ::: "memory");
      __builtin_amdgcn_s_barrier();
    };
#pragma unroll 1
    for (int s = 0; s < STEPS; s += 2){
      body(s,     P0, P1, P3, Q0, Q1, Q3);
      body(s + 1, Q0, Q1, Q3, P0, P1, P3);
    }
  } else {
    unsigned G[DEPTH][12];
    auto load_gi = [&](int d, int S){
#pragma unroll
      for (int r = 0; r < 4; ++r){
        const float* p = gi_f32 + (S*64 + n0 + q*4 + r)*384 + w16c;
        G[d][r]     = __float_as_uint(p[0]);
        G[d][4 + r] = __float_as_uint(p[128]);
        G[d][8 + r] = __float_as_uint(p[256]);
      }
    };
    auto body = [&](int S, int d){
      const int cur = S & 1, nxt = cur ^ 1;
      bf16x8 A[4];
#pragma unroll
      for (int kt = 0; kt < 4; ++kt)
        A[kt] = *(const bf16x8*)&hbuf[cur][hchunk(c, kt*4 + q)];
      f32x4 D[3];
#pragma unroll
      for (int r = 0; r < 4; ++r){
        D[0][r] = __uint_as_float(G[d][r]);
        D[1][r] = __uint_as_float(G[d][4 + r]);
        D[2][r] = bn;
      }
#pragma unroll
      for (int g = 0; g < 3; ++g)
#pragma unroll
        for (int kt = 0; kt < 4; ++kt)
          D[g] = __builtin_amdgcn_mfma_f32_16x16x32_bf16(A[kt], Bh[g][kt], D[g], 0,0,0);
#pragma unroll
      for (int r = 0; r < 4; ++r){
        float gn = __uint_as_float(G[d][8 + r]);
        float rr = sigm(D[0][r]);
        float z  = sigm(D[1][r]);
        float nn = tanh_fast(gn + rr * D[2][r]);
        h_old[r] = nn + z*(h_old[r] - nn);
      }
      if (S + DEPTH < STEPS) load_gi(d, S + DEPTH);
#pragma unroll
      for (int r = 0; r < 4; ++r)
        hbuf[nxt][hchunk(q*4 + r, w*2 + (c >> 3)) + (c & 7)] = bf1(h_old[r]);
      asm volatile("s_waitcnt lgkmcnt(0)" ::: "memory");
      __builtin_amdgcn_s_barrier();
    };
#pragma unroll
    for (int d = 0; d < DEPTH; ++d) load_gi(d, d);
#pragma unroll 1
    for (int s = 0; s < STEPS; s += DEPTH){
#pragma unroll
      for (int d = 0; d < DEPTH; ++d) body(s + d, d);
    }
  }

  if constexpr (FINAL){
    // fused final: out[b][j] = h[b] . fw[j] + fb[j]   (h in hbuf[STEPS&1])
    if (tid < 48){
      int row = tid / 3, j = tid % 3;
      float acc = fb[j];
      const int cur = STEPS & 1;
      for (int k = 0; k < 128; ++k)
        acc += bf2f(hbuf[cur][hchunk(row, k >> 3) + (k & 7)]) * fw[j*128 + k];
      outp[(n0 + row)*3 + j] = acc;
    }
  } else {
#pragma unroll
    for (int r = 0; r < 4; ++r)
      hout[(n0 + q*4 + r)*128 + w16c] = h_old[r];
  }
}

// ---------------- K2: cgi = M2 @ [hT;ind] + b2 ----------------
__global__ __launch_bounds__(256)
void cgi_kernel(const float* __restrict__ hT, const float* __restrict__ M2,
                const float* __restrict__ b2, float* __restrict__ cgi)
{
  const int tid = threadIdx.x;
  const int w = tid >> 6, lane = tid & 63, c = lane & 15, q = lane >> 4;
  const int n0 = (blockIdx.x*4 + w) * 16;       // 200 tiles of 16 rows (n = b*50+c)
  bf16x8 A[4];
#pragma unroll
  for (int kt = 0; kt < 4; ++kt){
    const f32x4* p = (const f32x4*)(hT + (n0 + c)*128 + kt*32 + q*8);
    A[kt] = pack8(p[0], p[1]);
  }
#pragma unroll 1
  for (int ot = 0; ot < 24; ++ot){
    f32x4 D = {0.f,0.f,0.f,0.f};
#pragma unroll
    for (int kt = 0; kt < 4; ++kt){
      const f32x4* p = (const f32x4*)(M2 + (ot*16 + c)*132 + kt*32 + q*8);
      bf16x8 Bf = pack8(p[0], p[1]);
      D = __builtin_amdgcn_mfma_f32_16x16x32_bf16(A[kt], Bf, D, 0,0,0);
    }
    int o = ot*16 + c;
    float bias = b2[o];
    float indv = M2[o*132 + 128];               // conclusion-indicator column
#pragma unroll
    for (int r = 0; r < 4; ++r){
      int n  = n0 + q*4 + r;
      int cc = n % 50, b = n / 50;
      float vv = D[r] + bias + (cc == 0 ? indv : 0.f);
      cgi[(cc*64 + b)*384 + o] = vv;            // stored [c][b] for the ctx scan
    }
  }
}

extern "C" void kernel_launch(void* const* d_in, const int* in_sizes, int n_in,
                              void* d_out, int out_size, void* d_ws, size_t ws_size,
                              hipStream_t stream)
{
  const int*   tok   = (const int*)  d_in[0];
  const float* emb   = (const float*)d_in[1];
  const float* awih  = (const float*)d_in[2];
  const float* awhh  = (const float*)d_in[3];
  const float* abih  = (const float*)d_in[4];
  const float* abhh  = (const float*)d_in[5];
  const float* ainit = (const float*)d_in[6];
  const float* cwih  = (const float*)d_in[7];
  const float* cwhh  = (const float*)d_in[8];
  const float* cbih  = (const float*)d_in[9];
  const float* cbhh  = (const float*)d_in[10];
  const float* cinit = (const float*)d_in[11];
  const float* pw    = (const float*)d_in[12];
  const float* pb    = (const float*)d_in[13];
  const float* fw    = (const float*)d_in[14];
  const float* fb    = (const float*)d_in[15];
  float* out = (float*)d_out;

  char* ws = (char*)d_ws;                       // needs ~6.8 MB
  float* hT  = (float*)(ws + 0);                              // 3200*128*4 = 1,638,400
  float* cgi = (float*)(ws + 1638400);                        // 3200*384*4 = 4,915,200
  float* M2  = (float*)(ws + 6553600);                        // 384*132*4  =   202,752
  float* b2  = (float*)(ws + 6756352);                        // 384*4

  m2_kernel<<<195, 256, 0, stream>>>(cwih, pw, pb, cbih, cbhh, M2, b2);
  gru_kernel<128, 2, true,  false><<<200, 512, 0, stream>>>(
      tok, emb, nullptr, awhh, awih, abih, abhh, ainit, hT, nullptr, nullptr, nullptr);
  cgi_kernel<<<50, 256, 0, stream>>>(hT, M2, b2, cgi);
  gru_kernel<50,  2, false, true ><<<4,   512, 0, stream>>>(
      nullptr, nullptr, cgi, cwhh, nullptr, nullptr, cbhh, cinit, nullptr, fw, fb, out);
}

// Round 13
// 165.394 us; speedup vs baseline: 1.9107x; 1.9107x over previous
//
#include <hip/hip_runtime.h>

// PosEvalModel: embed-gather + GRU(L=128, N=3200) + proj + GRU(C=50, N=64) + final.
// v13 = r11 (proven 181.5us) + cgi FUSED into the ast-gru epilogue:
//   each ast block's final 16 h-rows sit in hbuf (bf16, same rounding cgi used) ->
//   compute cgi[16 rows x 384] in-place (A from hbuf, B from M2, bias added after,
//   bit-identical fp order), write straight to the ctx-scan layout. Deletes the cgi
//   kernel, its launch gap, and the hT round-trip.
//  K0 m2:  M2[384][129] = ctx_w_ih @ proj_w (+b2)
//  K1 gru<EMB>: ast recurrence (8 waves, 16 rows, 24 MFMA/wave/step) + cgi epilogue
//  K2 gru<!EMB>: ctx recurrence (r11-exact) + fused final matmul epilogue

#define V_VOCAB 100008

typedef __attribute__((ext_vector_type(8))) short bf16x8;
typedef __attribute__((ext_vector_type(4))) float f32x4;

__device__ __forceinline__ unsigned pk_bf16(float lo, float hi){
  unsigned r;
  asm("v_cvt_pk_bf16_f32 %0, %1, %2" : "=v"(r) : "v"(lo), "v"(hi));
  return r;
}
__device__ __forceinline__ unsigned short bf1(float x){   // f32->bf16 via HW cvt
  return (unsigned short)pk_bf16(x, x);
}
__device__ __forceinline__ bf16x8 pack8(f32x4 a, f32x4 b){
  union { unsigned u[4]; bf16x8 v; } x;
  x.u[0] = pk_bf16(a[0], a[1]);
  x.u[1] = pk_bf16(a[2], a[3]);
  x.u[2] = pk_bf16(b[0], b[1]);
  x.u[3] = pk_bf16(b[2], b[3]);
  return x.v;
}
__device__ __forceinline__ float bf2f(unsigned bits){
  union { unsigned u; float f; } x; x.u = bits << 16; return x.f;
}
__device__ __forceinline__ float fexp2(float x){ return __builtin_amdgcn_exp2f(x); }
__device__ __forceinline__ float frcp(float x){ return __builtin_amdgcn_rcpf(x); }
__device__ __forceinline__ float sigm(float x){ return frcp(1.f + fexp2(x * -1.44269504089f)); }
__device__ __forceinline__ float tanh_fast(float x){
  float t = fexp2(x * -2.88539008178f);        // e^{-2x}
  return (1.f - t) * frcp(1.f + t);
}
// element index of the 8-elem chunk (row, ch=k>>3) in a 16x128 bf16 tile, swizzled
__device__ __forceinline__ int hchunk(int row, int ch){
  return row*128 + ((ch ^ row ^ (row >> 2)) & 15)*8;
}

// ---------------- K0: M2 = ctx_w_ih @ proj_w (+b2) ----------------
__global__ __launch_bounds__(256)
void m2_kernel(const float* __restrict__ wcih, const float* __restrict__ pw,
               const float* __restrict__ pb, const float* __restrict__ bcih,
               const float* __restrict__ bchh, float* __restrict__ M2,
               float* __restrict__ b2)
{
  int t = blockIdx.x*256 + threadIdx.x;
  if (t >= 384*130) return;
  int o = t / 130, kk = t % 130;
  const float* wr = wcih + o*128;
  if (kk < 129){
    float acc = 0.f;
    for (int m = 0; m < 128; ++m) acc += wr[m] * pw[m*129 + kk];
    M2[o*132 + kk] = acc;                       // padded stride 132
  } else {
    float acc = bcih[o] + (o < 256 ? bchh[o] : 0.f);
    for (int m = 0; m < 128; ++m) acc += wr[m] * pb[m];
    b2[o] = acc;
  }
}

// ---------------- K1/K2: GRU recurrence (8 waves / 512 thr / 16 rows) ----------------
// Wave w owns gate-cols {w*16..w*16+15} (r,z,n).
// EMB: r11-exact deep-x pipeline (xbuf written 2 steps ahead; Ax[s+1] read pre-barrier;
//      x-MFMAs first at barrier-exit) + fused cgi epilogue.
// !EMB: r11-exact DEPTH-deep gi_f32 prefetch (ctx path) + fused final epilogue.
template<int STEPS, int DEPTH, bool EMB, bool FINAL>
__global__ __launch_bounds__(512, 1)
void gru_kernel(const int* __restrict__ tok_ids,
                const float* __restrict__ emb,
                const float* __restrict__ gi_f32,
                const float* __restrict__ whh,
                const float* __restrict__ wih,
                const float* __restrict__ bih,
                const float* __restrict__ bhh,
                const float* __restrict__ hinit,
                const float* __restrict__ M2,   // EMB epilogue
                const float* __restrict__ b2,   // EMB epilogue
                float* __restrict__ cgi,        // EMB epilogue out
                const float* __restrict__ fw,
                const float* __restrict__ fb,
                float* __restrict__ outp)
{
  __shared__ unsigned short hbuf[2][2048];      // [buf][16 rows x 128 k] bf16, swizzled
  __shared__ int toks[EMB ? 2048 : 2];          // emb byte-offsets [16 rows][128 steps]
  __shared__ unsigned short xbuf[EMB ? 4096 : 2]; // [buf][16 x 128] bf16 emb, swizzled
  const int tid = threadIdx.x;
  const int w = tid >> 6, lane = tid & 63, c = lane & 15, q = lane >> 4;
  const int n0 = blockIdx.x * 16;
  const int w16c = w*16 + c;

  if constexpr (EMB){
    for (int i = tid; i < 2048; i += 512) toks[i] = tok_ids[n0*128 + i] << 9;  // *512B
  }
  // weight fragments, UNSCALED bf16 (B layout: col = lane&15 = o, k = kt*32 + q*8 + e)
  bf16x8 Bh[3][4], Bx[3][4];
#pragma unroll
  for (int g = 0; g < 3; ++g)
#pragma unroll
    for (int kt = 0; kt < 4; ++kt){
      int o = g*128 + w16c;
      const f32x4* ph = (const f32x4*)(whh + o*128 + kt*32 + q*8);
      Bh[g][kt] = pack8(ph[0], ph[1]);
      if constexpr (EMB){
        const f32x4* px = (const f32x4*)(wih + o*128 + kt*32 + q*8);
        Bx[g][kt] = pack8(px[0], px[1]);
      }
    }
  float cr, cz, cin;
  const float bn = bhh[256 + w16c];             // b_hh_n (multiplied by r)
  if constexpr (EMB){
    cr  = bih[w16c]       + bhh[w16c];          // b_ih_r + b_hh_r
    cz  = bih[128 + w16c] + bhh[128 + w16c];    // b_ih_z + b_hh_z
    cin = bih[256 + w16c];                      // b_ih_n (outside r*(...))
  }
  float h_old[4];
  {
    float h0 = hinit[w16c];
#pragma unroll
    for (int r = 0; r < 4; ++r) h_old[r] = h0;
  }
  for (int i = tid; i < 2048; i += 512){
    int row = i >> 7, k = i & 127;
    hbuf[0][hchunk(row, k >> 3) + (k & 7)] = bf1(hinit[k]);
  }
  __syncthreads();

  if constexpr (EMB){
    // stager slot: 512 threads = 16 rows x 32 f32x4 chunks
    const int srow = tid >> 5, spos = tid & 31;
    const int sdst = hchunk(srow, spos >> 1) + (spos & 1)*4;  // 8B-aligned short idx
    f32x4 EA, EB, T0, T1;
    auto load_x = [&](f32x4& E, int t){
      int tt = t < STEPS ? t : STEPS - 1;       // tail-clamped, uniform count
      E = *(const f32x4*)((const char*)emb
            + (size_t)(unsigned)toks[srow*128 + tt] + spos*16);
    };
    auto write_x = [&](const f32x4& E, int b){
      unsigned long long v = ((unsigned long long)pk_bf16(E[2], E[3]) << 32)
                           | pk_bf16(E[0], E[1]);
      *(unsigned long long*)&xbuf[b*2048 + sdst] = v;
    };
    // prologue: xbuf[0]=x[0], xbuf[1]=x[1]; EA=x[2], EB=x[3] in flight
    load_x(T0, 0);
    load_x(T1, 1);
    write_x(T0, 0);
    write_x(T1, 1);
    load_x(EA, 2);
    load_x(EB, 3);
    __syncthreads();                            // xbuf[0..1] visible to all
    bf16x8 AxC[4], AxN[4];
#pragma unroll
    for (int kt = 0; kt < 4; ++kt)              // preload Ax for step 0
      AxC[kt] = *(const bf16x8*)&xbuf[hchunk(c, kt*4 + q)];
    __syncthreads();                            // preload reads done before body(0)'s write

    auto body = [&](int s, f32x4& Ew){
      const int cur = s & 1, nxt = cur ^ 1;
      // x-chains first: AxC already in registers -> zero LDS wait at barrier-exit
      f32x4 D0, D1, D2, D3;
#pragma unroll
      for (int r = 0; r < 4; ++r){ D0[r] = cr; D1[r] = cz; D2[r] = bn; D3[r] = cin; }
#pragma unroll
      for (int kt = 0; kt < 4; ++kt){
        D0 = __builtin_amdgcn_mfma_f32_16x16x32_bf16(AxC[kt], Bx[0][kt], D0, 0,0,0);
        D1 = __builtin_amdgcn_mfma_f32_16x16x32_bf16(AxC[kt], Bx[1][kt], D1, 0,0,0);
        D3 = __builtin_amdgcn_mfma_f32_16x16x32_bf16(AxC[kt], Bx[2][kt], D3, 0,0,0);
      }
      bf16x8 Ah[4];
#pragma unroll
      for (int kt = 0; kt < 4; ++kt)
        Ah[kt] = *(const bf16x8*)&hbuf[cur][hchunk(c, kt*4 + q)];
#pragma unroll
      for (int kt = 0; kt < 4; ++kt){
        D0 = __builtin_amdgcn_mfma_f32_16x16x32_bf16(Ah[kt], Bh[0][kt], D0, 0,0,0);
        D1 = __builtin_amdgcn_mfma_f32_16x16x32_bf16(Ah[kt], Bh[1][kt], D1, 0,0,0);
        D2 = __builtin_amdgcn_mfma_f32_16x16x32_bf16(Ah[kt], Bh[2][kt], D2, 0,0,0);
      }
      // pre-barrier: read Ax for step s+1 (xbuf[nxt], written at s-1, synced)
#pragma unroll
      for (int kt = 0; kt < 4; ++kt)
        AxN[kt] = *(const bf16x8*)&xbuf[nxt*2048 + hchunk(c, kt*4 + q)];
      // write x[s+2] into xbuf[cur] (x[s] consumed into regs by all waves at s-1)
      write_x(Ew, cur);
      load_x(Ew, s + 4);                        // refill; 2-step slack, vmcnt counted
      // gates: r3-exact (D row = q*4+r, col = w16c -> lane-local)
#pragma unroll
      for (int r = 0; r < 4; ++r){
        float rr = sigm(D0[r]);
        float z  = sigm(D1[r]);
        float nn = tanh_fast(D3[r] + rr * D2[r]);
        h_old[r] = nn + z*(h_old[r] - nn);
      }
#pragma unroll
      for (int r = 0; r < 4; ++r)
        hbuf[nxt][hchunk(q*4 + r, w*2 + (c >> 3)) + (c & 7)] = bf1(h_old[r]);
      asm volatile("s_waitcnt lgkmcnt(0)" ::: "memory");
      __builtin_amdgcn_s_barrier();
#pragma unroll
      for (int kt = 0; kt < 4; ++kt) AxC[kt] = AxN[kt];
    };
#pragma unroll 1
    for (int s = 0; s < STEPS; s += 2){
      body(s,     EA);                          // even s: write x[s+2], refill EA=x[s+4]
      body(s + 1, EB);                          // odd  s
    }

    // ---- fused cgi epilogue: cgi rows n0..n0+15 from hbuf[STEPS&1] ----
    // A bit-identical to the old cgi kernel (hbuf = bf1(h) = pack8 RNE of hT).
    {
      const int fin = STEPS & 1;
      bf16x8 A[4];
#pragma unroll
      for (int kt = 0; kt < 4; ++kt)
        A[kt] = *(const bf16x8*)&hbuf[fin][hchunk(c, kt*4 + q)];
#pragma unroll
      for (int g = 0; g < 3; ++g){
        int o = g*128 + w16c;
        f32x4 D = {0.f,0.f,0.f,0.f};
#pragma unroll
        for (int kt = 0; kt < 4; ++kt){
          const f32x4* p = (const f32x4*)(M2 + o*132 + kt*32 + q*8);
          bf16x8 Bf = pack8(p[0], p[1]);
          D = __builtin_amdgcn_mfma_f32_16x16x32_bf16(A[kt], Bf, D, 0,0,0);
        }
        float bias = b2[o];
        float indv = M2[o*132 + 128];           // conclusion-indicator column
#pragma unroll
        for (int r = 0; r < 4; ++r){
          int n  = n0 + q*4 + r;
          int cc = n % 50, b = n / 50;
          float vv = D[r] + bias + (cc == 0 ? indv : 0.f);
          cgi[(cc*64 + b)*384 + o] = vv;        // [c][b] layout for the ctx scan
        }
      }
    }
  } else {
    unsigned G[DEPTH][12];
    auto load_gi = [&](int d, int S){
#pragma unroll
      for (int r = 0; r < 4; ++r){
        const float* p = gi_f32 + (S*64 + n0 + q*4 + r)*384 + w16c;
        G[d][r]     = __float_as_uint(p[0]);
        G[d][4 + r] = __float_as_uint(p[128]);
        G[d][8 + r] = __float_as_uint(p[256]);
      }
    };
    auto body = [&](int S, int d){
      const int cur = S & 1, nxt = cur ^ 1;
      bf16x8 A[4];
#pragma unroll
      for (int kt = 0; kt < 4; ++kt)
        A[kt] = *(const bf16x8*)&hbuf[cur][hchunk(c, kt*4 + q)];
      f32x4 D[3];
#pragma unroll
      for (int r = 0; r < 4; ++r){
        D[0][r] = __uint_as_float(G[d][r]);
        D[1][r] = __uint_as_float(G[d][4 + r]);
        D[2][r] = bn;
      }
#pragma unroll
      for (int g = 0; g < 3; ++g)
#pragma unroll
        for (int kt = 0; kt < 4; ++kt)
          D[g] = __builtin_amdgcn_mfma_f32_16x16x32_bf16(A[kt], Bh[g][kt], D[g], 0,0,0);
#pragma unroll
      for (int r = 0; r < 4; ++r){
        float gn = __uint_as_float(G[d][8 + r]);
        float rr = sigm(D[0][r]);
        float z  = sigm(D[1][r]);
        float nn = tanh_fast(gn + rr * D[2][r]);
        h_old[r] = nn + z*(h_old[r] - nn);
      }
      if (S + DEPTH < STEPS) load_gi(d, S + DEPTH);
#pragma unroll
      for (int r = 0; r < 4; ++r)
        hbuf[nxt][hchunk(q*4 + r, w*2 + (c >> 3)) + (c & 7)] = bf1(h_old[r]);
      asm volatile("s_waitcnt lgkmcnt(0)" ::: "memory");
      __builtin_amdgcn_s_barrier();
    };
#pragma unroll
    for (int d = 0; d < DEPTH; ++d) load_gi(d, d);
#pragma unroll 1
    for (int s = 0; s < STEPS; s += DEPTH){
#pragma unroll
      for (int d = 0; d < DEPTH; ++d) body(s + d, d);
    }
  }

  if constexpr (FINAL){
    // fused final: out[b][j] = h[b] . fw[j] + fb[j]   (h in hbuf[STEPS&1])
    if (tid < 48){
      int row = tid / 3, j = tid % 3;
      float acc = fb[j];
      const int cur = STEPS & 1;
      for (int k = 0; k < 128; ++k)
        acc += bf2f(hbuf[cur][hchunk(row, k >> 3) + (k & 7)]) * fw[j*128 + k];
      outp[(n0 + row)*3 + j] = acc;
    }
  }
}

extern "C" void kernel_launch(void* const* d_in, const int* in_sizes, int n_in,
                              void* d_out, int out_size, void* d_ws, size_t ws_size,
                              hipStream_t stream)
{
  const int*   tok   = (const int*)  d_in[0];
  const float* emb   = (const float*)d_in[1];
  const float* awih  = (const float*)d_in[2];
  const float* awhh  = (const float*)d_in[3];
  const float* abih  = (const float*)d_in[4];
  const float* abhh  = (const float*)d_in[5];
  const float* ainit = (const float*)d_in[6];
  const float* cwih  = (const float*)d_in[7];
  const float* cwhh  = (const float*)d_in[8];
  const float* cbih  = (const float*)d_in[9];
  const float* cbhh  = (const float*)d_in[10];
  const float* cinit = (const float*)d_in[11];
  const float* pw    = (const float*)d_in[12];
  const float* pb    = (const float*)d_in[13];
  const float* fw    = (const float*)d_in[14];
  const float* fb    = (const float*)d_in[15];
  float* out = (float*)d_out;

  char* ws = (char*)d_ws;                       // needs ~5.2 MB
  float* cgi = (float*)(ws + 0);                              // 3200*384*4 = 4,915,200
  float* M2  = (float*)(ws + 4915200);                        // 384*132*4  =   202,752
  float* b2  = (float*)(ws + 5117952);                        // 384*4

  m2_kernel<<<195, 256, 0, stream>>>(cwih, pw, pb, cbih, cbhh, M2, b2);
  gru_kernel<128, 2, true,  false><<<200, 512, 0, stream>>>(
      tok, emb, nullptr, awhh, awih, abih, abhh, ainit,
      M2, b2, cgi, nullptr, nullptr, nullptr);
  gru_kernel<50,  2, false, true ><<<4,   512, 0, stream>>>(
      nullptr, nullptr, cgi, cwhh, nullptr, nullptr, cbhh, cinit,
      nullptr, nullptr, nullptr, fw, fb, out);
}